// Round 6
// baseline (1739.776 us; speedup 1.0000x reference)
//
#include <hip/hip_runtime.h>
#include <cstdint>
#include <cstddef>

#define BT_TOT 64000
#define FIN    1024
#define GV     640
#define NV     320
#define VD     128
#define INV_BT (1.0f/64000.0f)

// Iteration = BK 32 (2 chunks of 16). 32 iterations.
// Wpk layout: [iter(32)][g(2)][chunk(2)][s(hi/lo)][320 cols x 2 k-halves x 16B]
#define ITER_B  81920
#define BUF_B   40960

typedef __attribute__((ext_vector_type(8))) __bf16 bf16x8;
typedef __attribute__((ext_vector_type(16))) float f32x16;

typedef __attribute__((address_space(1))) void gvoid_t;
typedef __attribute__((address_space(3))) void lvoid_t;

__device__ inline short f2bf(float x) {            // RNE fp32 -> bf16 bits
    unsigned int u = __float_as_uint(x);
    unsigned int r = (u + 0x7fffu + ((u >> 16) & 1u)) >> 16;
    return (short)r;
}
__device__ inline float bf2f(short h) {
    return __uint_as_float(((unsigned int)(unsigned short)h) << 16);
}
__device__ inline bf16x8 ld_frag(const char* p) {
    union { uint4 u; bf16x8 v; } t;
    t.u = *(const uint4*)p;
    return t.v;
}
__device__ __forceinline__ void glds16(const void* g, void* l) {
    __builtin_amdgcn_global_load_lds((gvoid_t*)g, (lvoid_t*)l, 16, 0, 0);
}
__device__ __forceinline__ void cvt8(const float4 f0, const float4 f1,
                                     bf16x8& hh, bf16x8& ll) {
    union { float4 f[2]; float s[8]; } ua; ua.f[0] = f0; ua.f[1] = f1;
    union { short s[8]; bf16x8 v; } uh, ul;
#pragma unroll
    for (int e = 0; e < 8; ++e) {
        const short hb = f2bf(ua.s[e]);
        uh.s[e] = hb;
        ul.s[e] = f2bf(ua.s[e] - bf2f(hb));
    }
    hh = uh.v; ll = ul.v;
}

// ---------- prep: split W into bf16 hi/lo, packed per-iteration ----------
__global__ __launch_bounds__(256) void prep(
    const float* __restrict__ W, char* __restrict__ Wpk,
    float* __restrict__ psum_g, int* __restrict__ cnt_g)
{
    const int t = blockIdx.x * 256 + threadIdx.x;
    if (t < GV) { psum_g[t] = 0.f; cnt_g[t] = 0; }
    const int r    = t >> 7;        // W row (out col) 0..639
    const int ck8  = t & 127;       // 8-elem chunk along k
    const int iter = ck8 >> 2;      // iteration 0..31
    const int c    = (ck8 >> 1) & 1;// chunk within iteration
    const int ch   = ck8 & 1;       // k-half within chunk (h)
    const int g    = (r >= NV) ? 1 : 0;
    const int cv   = r - g * NV;    // col within group 0..319
    const float* src = W + (size_t)r * FIN + (size_t)ck8 * 8;
    const float4 a = ((const float4*)src)[0];
    const float4 b = ((const float4*)src)[1];
    float xs[8] = {a.x, a.y, a.z, a.w, b.x, b.y, b.z, b.w};
    short hi[8], lo[8];
#pragma unroll
    for (int e = 0; e < 8; ++e) {
        hi[e] = f2bf(xs[e]);
        lo[e] = f2bf(xs[e] - bf2f(hi[e]));
    }
    char* dst = Wpk + (size_t)iter * ITER_B + (size_t)g * BUF_B + (size_t)c * 20480
                    + (size_t)(cv * 32 + ch * 16);
    *(uint4*)dst           = *(uint4*)hi;   // s=0 (hi)
    *(uint4*)(dst + 10240) = *(uint4*)lo;   // s=1 (lo)
}

// ---------- fused: 32x32x16 bf16-triple GEMM, free-running 1-barrier/iter ----------
// Grid 512 (500 active) x 512 thr. Block = 256 rows x 320 cols (one group).
// 8 waves = 4 row-stripes (64 rows, 2 Mt) x 2 col-stripes (160 cols, 5 Nt).
// acc[2][5] = 160; B-frag LDS reads halved vs 8x1 mapping (4-way sharing).
// One s_barrier per iter; staging vmcnt counted via [glds -> A-loads] issue order.
__global__ __launch_bounds__(512) void fused(
    const float* __restrict__ X, const char* __restrict__ Wpk,
    const float* __restrict__ bias, const float* __restrict__ gumbel,
    const float* __restrict__ codebook, float* __restrict__ q,
    float* __restrict__ psum_g, int* __restrict__ cnt_g)
{
    __shared__ __align__(16) char smem[2 * BUF_B];   // 80 KB

    // XCD-aware swizzle: (rb, g=0/1) pair lands on same XCD; 12 inert blocks.
    const int id = blockIdx.x;
    const int linear = (id & 7) * 64 + (id >> 3);
    if (linear >= 500) return;
    const int rb = linear >> 1, g = linear & 1;

    const int tid  = threadIdx.x;
    const int lane = tid & 63, wave = tid >> 6;
    const int rs = wave >> 1, cs = wave & 1;           // row-stripe, col-stripe
    const int cl = lane & 31, h = lane >> 5;
    const int row0 = rb * 256;
    const int bofs = cs * 5120 + cl * 32 + h * 16;     // B-frag byte base in s-region

    f32x16 acc[2][5];
#pragma unroll
    for (int mt = 0; mt < 2; ++mt)
#pragma unroll
        for (int nt = 0; nt < 5; ++nt) acc[mt][nt] = (f32x16)0.0f;

    const float* ap0 = X + (size_t)(row0 + rs * 64 + cl) * FIN + h * 8;   // mt=0
    const float* ap1 = ap0 + (size_t)32 * FIN;                            // mt=1
    const char*  wbase = Wpk + (size_t)g * BUF_B;

    // A regs: xa_c0/c1 = current iter, xn_c0/c1 = next iter ([mt][half])
    float4 xa_c0[2][2], xa_c1[2][2], xn_c0[2][2], xn_c1[2][2];

    // ---- prologue: glds iter0 FIRST, then A(iter0) loads (order matters!) ----
    {
#pragma unroll
        for (int j = 0; j < 5; ++j)
            glds16(wbase + (size_t)(tid + 512 * j) * 16, smem + (tid + 512 * j) * 16);
        __builtin_amdgcn_sched_barrier(0);
        xa_c0[0][0] = *(const float4*)(ap0);      xa_c0[0][1] = *(const float4*)(ap0 + 4);
        xa_c0[1][0] = *(const float4*)(ap1);      xa_c0[1][1] = *(const float4*)(ap1 + 4);
        xa_c1[0][0] = *(const float4*)(ap0 + 16); xa_c1[0][1] = *(const float4*)(ap0 + 20);
        xa_c1[1][0] = *(const float4*)(ap1 + 16); xa_c1[1][1] = *(const float4*)(ap1 + 20);
    }

    // ---- main loop: 32 iterations, ONE barrier each, free-running waves ----
    for (int i = 0; i < 32; ++i) {
        // staging of buf[i&1] (glds, older than the <=8 A-loads in flight) done?
        asm volatile("s_waitcnt vmcnt(8)" ::: "memory");
        __builtin_amdgcn_s_barrier();
        __builtin_amdgcn_sched_barrier(0);

        const char* bufc = smem + (i & 1) * BUF_B;
        char* bufn = smem + ((i + 1) & 1) * BUF_B;
        const char* wsrc = wbase + (size_t)(i + 1) * ITER_B;
        const bool more = (i < 31);

        if (more) {
#pragma unroll
            for (int j = 0; j < 5; ++j)
                glds16(wsrc + (size_t)(tid + 512 * j) * 16, bufn + (tid + 512 * j) * 16);
            __builtin_amdgcn_sched_barrier(0);
            // A-loads chunk0 for next iter (issued AFTER glds -> counted waits)
            const float* n0 = ap0 + (i + 1) * 32;
            const float* n1 = ap1 + (i + 1) * 32;
            xn_c0[0][0] = *(const float4*)(n0);  xn_c0[0][1] = *(const float4*)(n0 + 4);
            xn_c0[1][0] = *(const float4*)(n1);  xn_c0[1][1] = *(const float4*)(n1 + 4);
            __builtin_amdgcn_sched_barrier(0);
        }

        // ---- chunk 0 ----
        bf16x8 bh[5], bl[5], ah[2], al[2];
#pragma unroll
        for (int n = 0; n < 5; ++n) {
            bh[n] = ld_frag(bufc + n * 1024 + bofs);
            bl[n] = ld_frag(bufc + 10240 + n * 1024 + bofs);
        }
        cvt8(xa_c0[0][0], xa_c0[0][1], ah[0], al[0]);
        cvt8(xa_c0[1][0], xa_c0[1][1], ah[1], al[1]);
        __builtin_amdgcn_s_setprio(1);
#pragma unroll
        for (int n = 0; n < 5; ++n) {
            acc[0][n] = __builtin_amdgcn_mfma_f32_32x32x16_bf16(ah[0], bh[n], acc[0][n], 0, 0, 0);
            acc[1][n] = __builtin_amdgcn_mfma_f32_32x32x16_bf16(ah[1], bh[n], acc[1][n], 0, 0, 0);
        }
#pragma unroll
        for (int n = 0; n < 5; ++n) {
            acc[0][n] = __builtin_amdgcn_mfma_f32_32x32x16_bf16(al[0], bh[n], acc[0][n], 0, 0, 0);
            acc[1][n] = __builtin_amdgcn_mfma_f32_32x32x16_bf16(al[1], bh[n], acc[1][n], 0, 0, 0);
        }
#pragma unroll
        for (int n = 0; n < 5; ++n) {
            acc[0][n] = __builtin_amdgcn_mfma_f32_32x32x16_bf16(ah[0], bl[n], acc[0][n], 0, 0, 0);
            acc[1][n] = __builtin_amdgcn_mfma_f32_32x32x16_bf16(ah[1], bl[n], acc[1][n], 0, 0, 0);
        }
        __builtin_amdgcn_s_setprio(0);
        __builtin_amdgcn_sched_barrier(0);

        // ---- chunk 1 ----
#pragma unroll
        for (int n = 0; n < 5; ++n) {
            bh[n] = ld_frag(bufc + 20480 + n * 1024 + bofs);
            bl[n] = ld_frag(bufc + 30720 + n * 1024 + bofs);
        }
        cvt8(xa_c1[0][0], xa_c1[0][1], ah[0], al[0]);
        cvt8(xa_c1[1][0], xa_c1[1][1], ah[1], al[1]);
        if (more) {   // A-loads chunk1 for next iter (after cvt consumed xa_c1)
            const float* n0 = ap0 + (i + 1) * 32;
            const float* n1 = ap1 + (i + 1) * 32;
            xn_c1[0][0] = *(const float4*)(n0 + 16); xn_c1[0][1] = *(const float4*)(n0 + 20);
            xn_c1[1][0] = *(const float4*)(n1 + 16); xn_c1[1][1] = *(const float4*)(n1 + 20);
        }
        __builtin_amdgcn_s_setprio(1);
#pragma unroll
        for (int n = 0; n < 5; ++n) {
            acc[0][n] = __builtin_amdgcn_mfma_f32_32x32x16_bf16(ah[0], bh[n], acc[0][n], 0, 0, 0);
            acc[1][n] = __builtin_amdgcn_mfma_f32_32x32x16_bf16(ah[1], bh[n], acc[1][n], 0, 0, 0);
        }
#pragma unroll
        for (int n = 0; n < 5; ++n) {
            acc[0][n] = __builtin_amdgcn_mfma_f32_32x32x16_bf16(al[0], bh[n], acc[0][n], 0, 0, 0);
            acc[1][n] = __builtin_amdgcn_mfma_f32_32x32x16_bf16(al[1], bh[n], acc[1][n], 0, 0, 0);
        }
#pragma unroll
        for (int n = 0; n < 5; ++n) {
            acc[0][n] = __builtin_amdgcn_mfma_f32_32x32x16_bf16(ah[0], bl[n], acc[0][n], 0, 0, 0);
            acc[1][n] = __builtin_amdgcn_mfma_f32_32x32x16_bf16(ah[1], bl[n], acc[1][n], 0, 0, 0);
        }
        __builtin_amdgcn_s_setprio(0);

#pragma unroll
        for (int mt = 0; mt < 2; ++mt)
#pragma unroll
            for (int hf = 0; hf < 2; ++hf) {
                xa_c0[mt][hf] = xn_c0[mt][hf];
                xa_c1[mt][hf] = xn_c1[mt][hf];
            }
    }

    // ---- epilogue (aliases smem; all K-loop LDS traffic complete) ----
    float* psum_l = (float*)(smem);          // [320] f32   @0
    int*   cnt_l  = (int*)(smem + 1280);     // [320] i32   @1280
    int*   gidx   = (int*)(smem + 2560);     // [256]       @2560
    float* sv  = (float*)(smem + 4096);      // [512] local max      (rloc*2+cs)
    int*   sc  = (int*)(smem + 6144);        // [512] local argmax
    float* sgv = (float*)(smem + 8192);      // [512] local gumbel max
    int*   sgc = (int*)(smem + 10240);       // [512] local gumbel argmax
    float* ss  = (float*)(smem + 12288);     // [512] local exp-sum (vs local max)

    __syncthreads();                         // all waves done with K-loop buffers
    for (int i = tid; i < NV; i += 512) { psum_l[i] = 0.f; cnt_l[i] = 0; }
    __syncthreads();

    // bias add (D layout 32x32: col = cl, row = (reg&3) + 8*(reg>>2) + 4*h)
#pragma unroll
    for (int nt = 0; nt < 5; ++nt) {
        const float bv = bias[g * NV + cs * 160 + nt * 32 + cl];
#pragma unroll
        for (int mt = 0; mt < 2; ++mt)
#pragma unroll
            for (int r = 0; r < 16; ++r) acc[mt][nt][r] += bv;
    }

    float pcol[5];
#pragma unroll
    for (int nt = 0; nt < 5; ++nt) pcol[nt] = 0.f;

#pragma unroll
    for (int mt = 0; mt < 2; ++mt) {
#pragma unroll
        for (int c0 = 0; c0 < 16; c0 += 4) {
            float bvv[4], gvv[4], sll[4];
            int bcc[4], gcc[4];
            // phase 1: local (this col-stripe) max/argmax + exp-sum vs local max
#pragma unroll
            for (int j = 0; j < 4; ++j) {
                const int reg = c0 + j;
                const int rloc = rs * 64 + mt * 32 + (reg & 3) + 8 * (reg >> 2) + 4 * h;
                const float* gp = gumbel + (size_t)(row0 + rloc) * GV + g * NV;
                float bestv = -3.4e38f, gbv = -3.4e38f;
                int bestc = 0, gbc = 0;
#pragma unroll
                for (int nt = 0; nt < 5; ++nt) {
                    const float v = acc[mt][nt][reg];
                    const int cc = cs * 160 + nt * 32 + cl;
                    const float tv = v + gp[cc];
                    if (v > bestv) { bestv = v; bestc = cc; }
                    if (tv > gbv)  { gbv = tv;  gbc = cc; }
                }
#pragma unroll
                for (int off = 1; off < 32; off <<= 1) {
                    const float v2 = __shfl_xor(bestv, off); const int c2 = __shfl_xor(bestc, off);
                    if (v2 > bestv || (v2 == bestv && c2 < bestc)) { bestv = v2; bestc = c2; }
                    const float g2 = __shfl_xor(gbv, off); const int gc2 = __shfl_xor(gbc, off);
                    if (g2 > gbv || (g2 == gbv && gc2 < gbc)) { gbv = g2; gbc = gc2; }
                }
                float s = 0.f;
#pragma unroll
                for (int nt = 0; nt < 5; ++nt) s += __expf(acc[mt][nt][reg] - bestv);
#pragma unroll
                for (int off = 1; off < 32; off <<= 1) s += __shfl_xor(s, off);
                bvv[j] = bestv; bcc[j] = bestc; gvv[j] = gbv; gcc[j] = gbc; sll[j] = s;
                if (cl == 0) {
                    const int si = rloc * 2 + cs;
                    sv[si] = bestv; sc[si] = bestc; sgv[si] = gbv; sgc[si] = gbc; ss[si] = s;
                }
            }
            __syncthreads();
            // phase 2: merge with partner col-stripe (online-softmax combine)
#pragma unroll
            for (int j = 0; j < 4; ++j) {
                const int reg = c0 + j;
                const int rloc = rs * 64 + mt * 32 + (reg & 3) + 8 * (reg >> 2) + 4 * h;
                const int pi = rloc * 2 + (cs ^ 1);
                const float pv = sv[pi]; const int pc = sc[pi];
                const float pgv = sgv[pi]; const int pgc = sgc[pi];
                const float ps = ss[pi];
                float m = bvv[j]; int mc = bcc[j];
                if (pv > m || (pv == m && pc < mc)) { m = pv; mc = pc; }
                float mg = gvv[j]; int mgc = gcc[j];
                if (pgv > mg || (pgv == mg && pgc < mgc)) { mg = pgv; mgc = pgc; }
                const float fl = __expf(bvv[j] - m);
                const float stot = sll[j] * fl + ps * __expf(pv - m);
                const float fscale = fl / stot;
#pragma unroll
                for (int nt = 0; nt < 5; ++nt)
                    pcol[nt] += __expf(acc[mt][nt][reg] - bvv[j]) * fscale;
                if (cs == 0 && cl == 0) {
                    atomicAdd(&cnt_l[mc], 1);
                    gidx[rloc] = mgc;
                }
            }
        }
    }

    // fold column sums over h, then into block accumulator
#pragma unroll
    for (int nt = 0; nt < 5; ++nt) {
        const float v = pcol[nt] + __shfl_xor(pcol[nt], 32);
        if (h == 0) atomicAdd(&psum_l[cs * 160 + nt * 32 + cl], v);
    }
    __syncthreads();

    // q gather: 256 rows x 128 dims (this block's group); 2 threads per row
    {
        const int row = tid >> 1, half = tid & 1;
        const int idx = g * NV + gidx[row];
        const float4* srcp = (const float4*)(codebook + (size_t)idx * VD + half * 64);
        float4* dstp = (float4*)(q + (size_t)(row0 + row) * 256 + g * VD + half * 64);
#pragma unroll
        for (int i = 0; i < 16; ++i) dstp[i] = srcp[i];
    }
    // flush block accumulators
    for (int i = tid; i < NV; i += 512) {
        atomicAdd(&psum_g[g * NV + i], psum_l[i]);
        atomicAdd(&cnt_g[g * NV + i], cnt_l[i]);
    }
}

// ---------- finalize ----------
__global__ void finalize(const int* __restrict__ cnt_g, const float* __restrict__ psum_g,
                         float* __restrict__ out_scalars)
{
    const int lane = threadIdx.x;   // 64 threads = 1 wave
    float hsum[2] = {0.f, 0.f}, p[2] = {0.f, 0.f};
    for (int i = lane; i < GV; i += 64) {
        const int g = i / NV;
        const float hp = (float)cnt_g[i] * INV_BT;
        const float ap = psum_g[i] * INV_BT;
        hsum[g] -= hp * logf(hp + 1e-7f);
        p[g]    -= ap * logf(ap + 1e-7f);
    }
#pragma unroll
    for (int off = 32; off > 0; off >>= 1) {
        hsum[0] += __shfl_xor(hsum[0], off); hsum[1] += __shfl_xor(hsum[1], off);
        p[0] += __shfl_xor(p[0], off);       p[1] += __shfl_xor(p[1], off);
    }
    if (lane == 0) {
        out_scalars[0] = expf(hsum[0]) + expf(hsum[1]);
        out_scalars[1] = expf(p[0]) + expf(p[1]);
    }
}

extern "C" void kernel_launch(void* const* d_in, const int* in_sizes, int n_in,
                              void* d_out, int out_size, void* d_ws, size_t ws_size,
                              hipStream_t stream)
{
    const float* X  = (const float*)d_in[0];   // [64000,1024]
    const float* W  = (const float*)d_in[1];   // [640,1024]
    const float* Bv = (const float*)d_in[2];   // [640]
    const float* CB = (const float*)d_in[3];   // [640,128]
    const float* GU = (const float*)d_in[4];   // [64000,640]

    float* q = (float*)d_out;                                  // [64000,256]
    float* out_scalars = (float*)d_out + (size_t)BT_TOT * 256; // 2 scalars

    char* ws = (char*)d_ws;
    float* psum_g = (float*)ws;                 // 640 floats
    int*   cnt_g  = (int*)(ws + 4096);          // 640 ints
    char*  Wpk    = ws + 8192;                  // 32 iters * 81920 B = 2.62 MB

    prep<<<320, 256, 0, stream>>>(W, Wpk, psum_g, cnt_g);
    fused<<<512, 512, 0, stream>>>(X, Wpk, Bv, GU, CB, q, psum_g, cnt_g);
    finalize<<<1, 64, 0, stream>>>(cnt_g, psum_g, out_scalars);
}